// Round 4
// baseline (650.199 us; speedup 1.0000x reference)
//
#include <hip/hip_runtime.h>
#include <hip/hip_bf16.h>

typedef __bf16 bf16x8 __attribute__((ext_vector_type(8)));
typedef float floatx4 __attribute__((ext_vector_type(4)));

// RNE fp32 -> bf16 (returns raw bits)
__device__ __forceinline__ unsigned f2bf(float f) {
    unsigned u = __float_as_uint(f);
    u += 0x7FFFu + ((u >> 16) & 1u);
    return u >> 16;
}

// -------- fused pre-pass: cast feat+centers fp32->bf16, fp32 row norms.
// One WAVE per row, no LDS, no __syncthreads.
__global__ __launch_bounds__(256) void cast_norm2(
    const float* __restrict__ feat, const float* __restrict__ cent,
    unsigned short* __restrict__ Ab, unsigned short* __restrict__ Bb,
    float* __restrict__ x2, float* __restrict__ c2, int M)
{
    const int wave = threadIdx.x >> 6;
    const int lane = threadIdx.x & 63;
    const int row  = blockIdx.x * 4 + wave;

    const float* src;
    unsigned short* dst;
    float* nrm;
    if (row < M) {
        src = feat + (size_t)row * 1024;
        dst = Ab   + (size_t)row * 1024;
        nrm = x2 + row;
    } else {
        const int r = row - M;
        src = cent + (size_t)r * 1024;
        dst = Bb   + (size_t)r * 1024;
        nrm = c2 + r;
    }

    const float4* s4 = (const float4*)src;   // 256 float4 per row
    uint2* d2 = (uint2*)dst;                 // 256 uint2 per row
    float s = 0.f;
#pragma unroll
    for (int j = 0; j < 4; ++j) {
        const float4 v = s4[j * 64 + lane];
        s += v.x * v.x + v.y * v.y + v.z * v.z + v.w * v.w;
        uint2 o;
        o.x = f2bf(v.x) | (f2bf(v.y) << 16);
        o.y = f2bf(v.z) | (f2bf(v.w) << 16);
        d2[j * 64 + lane] = o;
    }
#pragma unroll
    for (int off = 32; off > 0; off >>= 1) s += __shfl_down(s, off);
    if (lane == 0) *nrm = s;
}

// ==================== 256x256 MFMA GEMM, REG-STAGED, 1 barrier per K-tile
// BM=BN=256, BK=64, 512 threads = 8 waves (2M x 4N), per-wave 128x64 output.
// LDS: 2 buffers x (A 32KB + B 32KB) = 128 KiB -> 1 block/CU.
//
// ROUND-4 REDESIGN: staging is global_load_dwordx4 -> VGPR -> ds_write_b128
// (no global_load_lds). Rationale: with LDS-DMA, the compiler's alias model
// (DMA writes LDS, every ds_read may alias) can insert its own conservative
// vmcnt waits before each phase's ds_reads, defeating counted-vmcnt and
// exposing one L2/L3 latency per phase (matches measured ~775cyc phases vs
// ~155cyc MFMA need; swizzle/barrier changes measured neutral -> stage path
// is critical). With reg-staging, global-load waits attach only to the
// ds_write that consumes the regs, placed ~1.75 tiles after issue.
//
// Tile pipeline (cur = t&1, nbuf = cur^1):
//   regs vA/vB hold tile t+1 (loaded during tile t-1)
//   [q0,q1 MFMA on cur] [sched_barrier] [q2 reads]
//   DSW: ds_write tile t+1 -> nbuf      (vmcnt waits land here, covered)
//   LOADR: issue tile t+2 global loads  (in flight across the barrier)
//   [q3 MFMA] LGKM0 BAR                 (ONE barrier per tile)
// Race-freedom: tile t reads only cur (stable), writes only nbuf (nobody
// reads it during t). Before the barrier each wave drained its own reads
// AND writes (lgkmcnt(0)); the barrier publishes all waves' writes of nbuf
// and all waves' read-completion of cur. So after it, reading nbuf and
// (next tile) overwriting cur are both safe. No other sync needed.
//
// Swizzle (full-spread, both sides in-kernel now): row r's logical 16B
// chunk j lives at slot j ^ ((r>>1)&3); reader wants chunk `quad` ->
// reads slot quad ^ ((r>>1)&3). Quarter-wave spreads over all 32 banks.
__global__ __launch_bounds__(512, 2) void dist_gemm(
    const unsigned short* __restrict__ A,   // [M][1024] bf16 (feat)
    const unsigned short* __restrict__ B,   // [N][1024] bf16 (centers)
    const float* __restrict__ x2,           // [M]
    const float* __restrict__ c2,           // [N]
    float* __restrict__ out,                // [M][N]
    int M, int N)
{
    __shared__ alignas(16) char lds_raw[131072];
    char* ldsb = lds_raw;
    const char* ldsc = lds_raw;

    const int tid  = threadIdx.x;
    const int wave = tid >> 6;       // 0..7
    const int lane = tid & 63;
    const int quad = lane >> 4;      // 0..3
    const int l16  = lane & 15;
    const int wm   = wave >> 2;      // 0..1 (M half)
    const int wn   = wave & 3;       // 0..3 (N quarter)

    // XCD-aware mapping: XCD owns a column slab; its B slab stays L2-resident;
    // all 8 XCDs sweep A rows in lockstep (A bf16 = 33.6 MB, L3-resident).
    const int gx  = gridDim.x;                      // N/256, multiple of 8
    const int lin = blockIdx.y * gx + blockIdx.x;
    const int colsPerXcd = gx >> 3;
    const int xcd  = lin & 7;
    const int slot = lin >> 3;
    const int bx = xcd * colsPerXcd + (slot % colsPerXcd);
    const int by = slot / colsPerXcd;

    const int blockRow = by * 256;
    const int blockCol = bx * 256;

    // ---- staging map: thread t covers k-panel wks=t>>8, row wrow=t&255,
    // one full 64B row-window per tile (4x 16B chunks), for both A and B.
    const int wks  = tid >> 8;          // 0..1
    const int wrow = tid & 255;         // 0..255
    const int rsw  = (wrow >> 1) & 3;   // write-side swizzle
    const int s0 = 0 ^ rsw, s1 = 1 ^ rsw, s2 = 2 ^ rsw, s3 = 3 ^ rsw;

    const uint4* pAg = (const uint4*)(A + (size_t)(blockRow + wrow) * 1024 + wks * 32);
    const uint4* pBg = (const uint4*)(B + (size_t)(blockCol + wrow) * 1024 + wks * 32);

    uint4 vA[4], vB[4];

// issue next-tile global loads (8x dwordx4), advance pointers (+128B = BK)
#define LOADR() do {                                                          \
        vA[0] = pAg[0]; vA[1] = pAg[1]; vA[2] = pAg[2]; vA[3] = pAg[3];       \
        vB[0] = pBg[0]; vB[1] = pBg[1]; vB[2] = pBg[2]; vB[3] = pBg[3];       \
        pAg += 8; pBg += 8;                                                   \
    } while (0)
// ds_write staged tile into buffer nb (swizzled slots)
#define DSW(nb) do {                                                          \
        uint4* _wa = (uint4*)(ldsb + (nb) * 65536 + wks * 16384 + wrow * 64); \
        uint4* _wb = (uint4*)(ldsb + (nb) * 65536 + 32768 + wks * 16384 + wrow * 64); \
        _wa[s0] = vA[0]; _wa[s1] = vA[1]; _wa[s2] = vA[2]; _wa[s3] = vA[3];   \
        _wb[s0] = vB[0]; _wb[s1] = vB[1]; _wb[s2] = vB[2]; _wb[s3] = vB[3];   \
    } while (0)

    // ---- fragment read addressing (full-spread swizzle on read)
    const int swq = quad ^ ((l16 >> 1) & 3);
    const int aRd = (wm * 128 + l16) * 64 + swq * 16;             // A region byte
    const int bRd = 32768 + (wn * 64 + l16) * 64 + swq * 16;      // B region byte

#define RD_A(buf, ks, mf) (*(const bf16x8*)(ldsc + (buf) * 65536 + (ks) * 16384 + (mf) * 1024 + aRd))
#define RD_B(buf, ks, nf) (*(const bf16x8*)(ldsc + (buf) * 65536 + (ks) * 16384 + (nf) * 1024 + bRd))

// aF[mf*2+ks], 8 reads (one A-quadrant, both k-panels)
#define LDA8(buf, mo) do {                                                    \
        aF[0] = RD_A(buf, 0, (mo) + 0); aF[2] = RD_A(buf, 0, (mo) + 1);       \
        aF[4] = RD_A(buf, 0, (mo) + 2); aF[6] = RD_A(buf, 0, (mo) + 3);       \
        aF[1] = RD_A(buf, 1, (mo) + 0); aF[3] = RD_A(buf, 1, (mo) + 1);       \
        aF[5] = RD_A(buf, 1, (mo) + 2); aF[7] = RD_A(buf, 1, (mo) + 3);       \
    } while (0)
// bb[nf*2+ks], 4 reads (one B-pair, both k-panels)
#define LDB4(bb, buf, no) do {                                                \
        bb[0] = RD_B(buf, 0, (no) + 0); bb[2] = RD_B(buf, 0, (no) + 1);       \
        bb[1] = RD_B(buf, 1, (no) + 0); bb[3] = RD_B(buf, 1, (no) + 1);       \
    } while (0)

#define BAR()    do { __builtin_amdgcn_s_barrier(); asm volatile("" ::: "memory"); } while (0)
#define LGKM0()  asm volatile("s_waitcnt lgkmcnt(0)" ::: "memory")

// one C-quadrant x K=64: 4 mf x 2 nf x 2 ks = 16 MFMA
#define MFMA_Q(mo, no, bb) do {                                               \
        __builtin_amdgcn_s_setprio(1);                                        \
        _Pragma("unroll")                                                     \
        for (int _m = 0; _m < 4; ++_m) {                                      \
            _Pragma("unroll")                                                 \
            for (int _n = 0; _n < 2; ++_n) {                                  \
                _Pragma("unroll")                                             \
                for (int _k = 0; _k < 2; ++_k) {                              \
                    acc[(mo) + _m][(no) + _n] =                               \
                        __builtin_amdgcn_mfma_f32_16x16x32_bf16(              \
                            aF[_m * 2 + _k], bb[_n * 2 + _k],                 \
                            acc[(mo) + _m][(no) + _n], 0, 0, 0);              \
                }                                                             \
            }                                                                 \
        }                                                                     \
        __builtin_amdgcn_s_setprio(0);                                        \
    } while (0)

    floatx4 acc[8][4];
#pragma unroll
    for (int i = 0; i < 8; ++i)
#pragma unroll
        for (int j = 0; j < 4; ++j) acc[i][j] = (floatx4){0.f, 0.f, 0.f, 0.f};

    bf16x8 aF[8], bL[4], bH[4];

// One K-tile on buffer `cur`. DW: ds_write tile t+1 to cur^1. DL: issue
// tile t+2 loads. sched_barrier caps fragment liveness (aF reuse point).
#define TILE(cur, DW, DL) do {                                                \
        LDA8(cur, 0); LDB4(bL, cur, 0); LDB4(bH, cur, 2);                     \
        MFMA_Q(0, 0, bL); MFMA_Q(0, 2, bH);                                   \
        __builtin_amdgcn_sched_barrier(0);                                    \
        LDA8(cur, 4);                                                         \
        MFMA_Q(4, 2, bH);                                                     \
        if (DW) DSW((cur) ^ 1);                                               \
        if (DL) LOADR();                                                      \
        MFMA_Q(4, 0, bL);                                                     \
        LGKM0(); BAR();                                                       \
    } while (0)

    // ---- prologue: tile0 -> regs -> buf0; issue tile1 loads; barrier.
    LOADR();         // tile 0
    DSW(0);
    LOADR();         // tile 1 (stays in flight into the loop)
    LGKM0(); BAR();

    // K = 1024 -> 16 K-tiles: 7 pairs + peeled tail (t=14 writes tile15,
    // loads nothing; t=15 writes/loads nothing).
#pragma unroll 1
    for (int it = 0; it < 7; ++it) {
        TILE(0, true, true);
        TILE(1, true, true);
    }
    TILE(0, true, false);
    TILE(1, false, false);

    // ---- epilogue: dist = x2[row] + c2[col] - 2*xc
    // C/D layout: col = lane&15, row = quad*4 + reg. Plain stores (L2 merges;
    // round-0 WRITE_SIZE was exactly the 262 MB ideal; NT regressed).
    float c2v[4];
#pragma unroll
    for (int nf = 0; nf < 4; ++nf) c2v[nf] = c2[blockCol + wn * 64 + nf * 16 + l16];

#pragma unroll
    for (int mf = 0; mf < 8; ++mf) {
        const int rowb = blockRow + wm * 128 + mf * 16 + quad * 4;
        float x2v[4];
#pragma unroll
        for (int r = 0; r < 4; ++r) x2v[r] = x2[rowb + r];
#pragma unroll
        for (int nf = 0; nf < 4; ++nf) {
            const int col = blockCol + wn * 64 + nf * 16 + l16;
            float* o = out + (size_t)rowb * N + col;
#pragma unroll
            for (int r = 0; r < 4; ++r)
                o[(size_t)r * N] = fmaf(-2.0f, acc[mf][nf][r], x2v[r] + c2v[nf]);
        }
    }

#undef TILE
#undef MFMA_Q
#undef LGKM0
#undef BAR
#undef LDB4
#undef LDA8
#undef RD_B
#undef RD_A
#undef DSW
#undef LOADR
}

// -------- fallback (only if ws_size too small / shape mismatch)
__global__ __launch_bounds__(256) void dist_fallback(
    const float* __restrict__ A, const float* __restrict__ B,
    float* __restrict__ out, int M, int N, int K)
{
    __shared__ float sA[64][17];
    __shared__ float sB[64][17];
    const int tid = threadIdx.x;
    const int tx = tid & 15;
    const int ty = tid >> 4;
    const int rowBase = blockIdx.y * 64;
    const int colBase = blockIdx.x * 64;
    float acc[4][4] = {};
    for (int k0 = 0; k0 < K; k0 += 16) {
        __syncthreads();
        {
            const int r = tid >> 2, c = (tid & 3) * 4;
            float4 va = *(const float4*)(A + (size_t)(rowBase + r) * K + k0 + c);
            sA[r][c] = va.x; sA[r][c + 1] = va.y; sA[r][c + 2] = va.z; sA[r][c + 3] = va.w;
            float4 vb = *(const float4*)(B + (size_t)(colBase + r) * K + k0 + c);
            sB[r][c] = vb.x; sB[r][c + 1] = vb.y; sB[r][c + 2] = vb.z; sB[r][c + 3] = vb.w;
        }
        __syncthreads();
#pragma unroll
        for (int kk = 0; kk < 16; kk++) {
            float ra[4], rb[4];
#pragma unroll
            for (int i = 0; i < 4; i++) ra[i] = sA[ty * 4 + i][kk];
#pragma unroll
            for (int j = 0; j < 4; j++) rb[j] = sB[tx * 4 + j][kk];
#pragma unroll
            for (int i = 0; i < 4; i++)
#pragma unroll
                for (int j = 0; j < 4; j++) {
                    float d = ra[i] - rb[j];
                    acc[i][j] = fmaf(d, d, acc[i][j]);
                }
        }
    }
#pragma unroll
    for (int i = 0; i < 4; i++)
#pragma unroll
        for (int j = 0; j < 4; j++)
            out[(size_t)(rowBase + ty * 4 + i) * N + (colBase + tx * 4 + j)] = acc[i][j];
}

extern "C" void kernel_launch(void* const* d_in, const int* in_sizes, int n_in,
                              void* d_out, int out_size, void* d_ws, size_t ws_size,
                              hipStream_t stream) {
    const float* feat = (const float*)d_in[0];
    const float* cent = (const float*)d_in[1];
    float* out = (float*)d_out;

    const int D = 1024;
    const int M = in_sizes[0] / D;   // 16384
    const int N = in_sizes[1] / D;   // 4096

    const size_t offA  = 0;
    const size_t offB  = offA + (size_t)M * D * sizeof(unsigned short);
    const size_t offX2 = offB + (size_t)N * D * sizeof(unsigned short);
    const size_t offC2 = offX2 + (size_t)M * sizeof(float);
    const size_t need  = offC2 + (size_t)N * sizeof(float);

    if (ws_size >= need && (M % 256) == 0 && (N % 2048) == 0) {
        unsigned short* Ab = (unsigned short*)((char*)d_ws + offA);
        unsigned short* Bb = (unsigned short*)((char*)d_ws + offB);
        float* x2 = (float*)((char*)d_ws + offX2);
        float* c2 = (float*)((char*)d_ws + offC2);

        cast_norm2<<<(M + N) / 4, 256, 0, stream>>>(feat, cent, Ab, Bb, x2, c2, M);
        dist_gemm<<<dim3(N / 256, M / 256), 512, 0, stream>>>(Ab, Bb, x2, c2, out, M, N);
    } else {
        dist_fallback<<<dim3(N / 64, M / 64), 256, 0, stream>>>(feat, cent, out, M, N, D);
    }
}

// Round 5
// 430.597 us; speedup vs baseline: 1.5100x; 1.5100x over previous
//
#include <hip/hip_runtime.h>
#include <hip/hip_bf16.h>

typedef __bf16 bf16x8 __attribute__((ext_vector_type(8)));
typedef float floatx4 __attribute__((ext_vector_type(4)));

// RNE fp32 -> bf16 (returns raw bits)
__device__ __forceinline__ unsigned f2bf(float f) {
    unsigned u = __float_as_uint(f);
    u += 0x7FFFu + ((u >> 16) & 1u);
    return u >> 16;
}

// async global->LDS, 16 bytes per lane; LDS base must be wave-uniform,
// HW writes lane l's 16B at base + l*16. Global src address is per-lane.
__device__ __forceinline__ void gl2lds(const void* g, void* l) {
    void* gnc = const_cast<void*>(g);
    __builtin_amdgcn_global_load_lds(
        (__attribute__((address_space(1))) void*)gnc,
        (__attribute__((address_space(3))) void*)l,
        16, 0, 0);
}

// -------- fused pre-pass: cast feat+centers fp32->bf16, fp32 row norms.
// One WAVE per row, no LDS, no __syncthreads.
__global__ __launch_bounds__(256) void cast_norm2(
    const float* __restrict__ feat, const float* __restrict__ cent,
    unsigned short* __restrict__ Ab, unsigned short* __restrict__ Bb,
    float* __restrict__ x2, float* __restrict__ c2, int M)
{
    const int wave = threadIdx.x >> 6;
    const int lane = threadIdx.x & 63;
    const int row  = blockIdx.x * 4 + wave;

    const float* src;
    unsigned short* dst;
    float* nrm;
    if (row < M) {
        src = feat + (size_t)row * 1024;
        dst = Ab   + (size_t)row * 1024;
        nrm = x2 + row;
    } else {
        const int r = row - M;
        src = cent + (size_t)r * 1024;
        dst = Bb   + (size_t)r * 1024;
        nrm = c2 + r;
    }

    const float4* s4 = (const float4*)src;   // 256 float4 per row
    uint2* d2 = (uint2*)dst;                 // 256 uint2 per row
    float s = 0.f;
#pragma unroll
    for (int j = 0; j < 4; ++j) {
        const float4 v = s4[j * 64 + lane];
        s += v.x * v.x + v.y * v.y + v.z * v.z + v.w * v.w;
        uint2 o;
        o.x = f2bf(v.x) | (f2bf(v.y) << 16);
        o.y = f2bf(v.z) | (f2bf(v.w) << 16);
        d2[j * 64 + lane] = o;
    }
#pragma unroll
    for (int off = 32; off > 0; off >>= 1) s += __shfl_down(s, off);
    if (lane == 0) *nrm = s;
}

// ==================== 256x256 MFMA GEMM with fused distance epilogue
// BM=BN=256, BK=64, 512 threads = 8 waves (2M x 4N), per-wave 128x64 output.
// LDS: 2 buffers x (A 32KB + B 32KB) = 128 KiB.
// Per buffer region: [2 k-panels][256 rows][32 bf16] (panel stride 16 KiB,
// row stride 64 B = 4 slots of 16B).
//
// Swizzle: slot = quad ^ ((row>>1)&3) -> quarter-wave b128 reads spread over
// all 32 banks at 2 lanes/bank (free). Staging keeps LDS dest linear
// (global_load_lds requirement), inverse-swizzles the per-lane GLOBAL source
// chunk: cswz = (lane&3) ^ ((lane>>3)&3)  (covered row = lane>>2).
//
// ROUND-5 CHANGES (base = round-3, which measured ~166us gemm):
// (1) XCD mapping flipped to A-ROW-SLABS. Old: XCD owns B col-slab (B = 8.4MB
//     small operand L2-resident) while every XCD streams all 33.5MB of A
//     through L3/HBM -> R0 FETCH 164MB vs 42 ideal; gate waits eat L3/HBM
//     latency. New: XCD owns 4-row-block A sub-slabs (2MB, L2-resident),
//     walks columns inner (B col-slab 512KB refetched from L3 per step).
//     Working set ~2.5MB < 4MB L2; A fetched from HBM ~once.
// (2) Both B half-tiles staged at p0 (was p0/p1): youngest B load at the
//     tile gate is 3 phases old, not 2.
//
// Barrier/wait scheme (unchanged from round 3): one s_barrier per phase END.
//   - MFMA depends only on this wave's own ds_reads (compiler lgkm waits +
//     explicit LGKM0 before the barrier).
//   - STAGE_A(buf) at p3 overwrites buf-A, last read at p2; p2's end barrier
//     certifies all waves' reads done.
//   - STAGE_B(obuf) at p0 overwrites obuf-B, last read in the previous tile,
//     published by that tile's end barrier.
//   - Fresh-tile reads need all waves' staging landed: per-wave vmcnt(4)
//     gate + tile-end barrier.
__global__ __launch_bounds__(512, 2) void dist_gemm(
    const unsigned short* __restrict__ A,   // [M][1024] bf16 (feat)
    const unsigned short* __restrict__ B,   // [N][1024] bf16 (centers)
    const float* __restrict__ x2,           // [M]
    const float* __restrict__ c2,           // [N]
    float* __restrict__ out,                // [M][N]
    int M, int N)
{
    __shared__ alignas(16) char lds_raw[131072];
    char* ldsb = lds_raw;
    const char* ldsc = lds_raw;

    const int tid  = threadIdx.x;
    const int wave = tid >> 6;       // 0..7
    const int lane = tid & 63;
    const int quad = lane >> 4;      // 0..3
    const int l16  = lane & 15;
    const int wm   = wave >> 2;      // 0..1 (M half)
    const int wn   = wave & 3;       // 0..3 (N quarter)

    // ---- XCD-aware mapping: A-row-slabs (round-5).
    // lin%8 -> XCD (round-robin dispatch). Each XCD owns gy/8 row-blocks,
    // processed as passes of 4 rows x all columns (rows innermost):
    // slot -> (r4 = slot&3, c = (slot>>2)%gx, p = slot/(4*gx)).
    const int gx  = gridDim.x;                      // N/256
    const int gy  = gridDim.y;                      // M/256, multiple of 32
    const int lin = blockIdx.y * gx + blockIdx.x;
    const int rpx  = gy >> 3;                       // row-blocks per XCD
    const int xcd  = lin & 7;
    const int slot = lin >> 3;
    const int r4   = slot & 3;
    const int c    = (slot >> 2) % gx;
    const int p    = slot / (4 * gx);
    const int by   = xcd * rpx + p * 4 + r4;
    const int bx   = c;

    const int blockRow = by * 256;
    const int blockCol = bx * 256;

    // ---- staging addressing (linear LDS dest, inverse-swizzled global src)
    // LDS(row, s) holds global k-chunk s ^ ((row>>1)&3).
    const int cswz = (lane & 3) ^ ((lane >> 3) & 3);
    const unsigned short* pA = A + (size_t)(blockRow + wave * 16 + (lane >> 2)) * 1024 + cswz * 8;
    const unsigned short* pB = B + (size_t)(blockCol + wave * 16 + (lane >> 2)) * 1024 + cswz * 8;
    const int stOff = wave * 1024;   // wave-uniform LDS chunk base (bytes)

// STAGE_A: both 128-row halves, both k-panels -> 4 gl2lds
#define STAGE_A(buf, kt) do {                                                 \
        const unsigned short* _s0 = pA + (size_t)(kt) * 64;                   \
        const unsigned short* _s1 = _s0 + 131072;                             \
        char* _d0 = ldsb + (buf) * 65536 + stOff;                             \
        gl2lds(_s0,      _d0);                                                \
        gl2lds(_s0 + 32, _d0 + 16384);                                        \
        gl2lds(_s1,      _d0 + 8192);                                         \
        gl2lds(_s1 + 32, _d0 + 8192 + 16384);                                 \
    } while (0)
// STAGE_B: one 128-row half (h) -> 2 gl2lds
#define STAGE_B(buf, kt, h) do {                                              \
        const unsigned short* _s = pB + (size_t)(h) * 131072 + (kt) * 64;     \
        char* _d = ldsb + (buf) * 65536 + 32768 + (h) * 8192 + stOff;         \
        gl2lds(_s,      _d);                                                  \
        gl2lds(_s + 32, _d + 16384);                                          \
    } while (0)

    // ---- fragment read addressing (full-spread swizzle on read)
    const int swq = quad ^ ((l16 >> 1) & 3);
    const int aRd = (wm * 128 + l16) * 64 + swq * 16;             // A region byte
    const int bRd = 32768 + (wn * 64 + l16) * 64 + swq * 16;      // B region byte

#define RD_A(buf, ks, mf) (*(const bf16x8*)(ldsc + (buf) * 65536 + (ks) * 16384 + (mf) * 1024 + aRd))
#define RD_B(buf, ks, nf) (*(const bf16x8*)(ldsc + (buf) * 65536 + (ks) * 16384 + (nf) * 1024 + bRd))

// aF[mf*2+ks], 8 reads (one A-quadrant, both k-panels)
#define LDA8(buf, mo) do {                                                    \
        aF[0] = RD_A(buf, 0, (mo) + 0); aF[2] = RD_A(buf, 0, (mo) + 1);       \
        aF[4] = RD_A(buf, 0, (mo) + 2); aF[6] = RD_A(buf, 0, (mo) + 3);       \
        aF[1] = RD_A(buf, 1, (mo) + 0); aF[3] = RD_A(buf, 1, (mo) + 1);       \
        aF[5] = RD_A(buf, 1, (mo) + 2); aF[7] = RD_A(buf, 1, (mo) + 3);       \
    } while (0)
// bb[nf*2+ks], 4 reads (one B-pair, both k-panels)
#define LDB4(bb, buf, no) do {                                                \
        bb[0] = RD_B(buf, 0, (no) + 0); bb[2] = RD_B(buf, 0, (no) + 1);       \
        bb[1] = RD_B(buf, 1, (no) + 0); bb[3] = RD_B(buf, 1, (no) + 1);       \
    } while (0)

#define BAR()    do { __builtin_amdgcn_s_barrier(); asm volatile("" ::: "memory"); } while (0)
#define LGKM0()  asm volatile("s_waitcnt lgkmcnt(0)" ::: "memory")
#define VMCNT4() asm volatile("s_waitcnt vmcnt(4)" ::: "memory")
#define VMCNT0() asm volatile("s_waitcnt vmcnt(0)" ::: "memory")

// one C-quadrant x K=64: 4 mf x 2 nf x 2 ks = 16 MFMA
#define MFMA_Q(mo, no, bb) do {                                               \
        __builtin_amdgcn_s_setprio(1);                                        \
        _Pragma("unroll")                                                     \
        for (int _m = 0; _m < 4; ++_m) {                                      \
            _Pragma("unroll")                                                 \
            for (int _n = 0; _n < 2; ++_n) {                                  \
                _Pragma("unroll")                                             \
                for (int _k = 0; _k < 2; ++_k) {                              \
                    acc[(mo) + _m][(no) + _n] =                               \
                        __builtin_amdgcn_mfma_f32_16x16x32_bf16(              \
                            aF[_m * 2 + _k], bb[_n * 2 + _k],                 \
                            acc[(mo) + _m][(no) + _n], 0, 0, 0);              \
                }                                                             \
            }                                                                 \
        }                                                                     \
        __builtin_amdgcn_s_setprio(0);                                        \
    } while (0)

    floatx4 acc[8][4];
#pragma unroll
    for (int i = 0; i < 8; ++i)
#pragma unroll
        for (int j = 0; j < 4; ++j) acc[i][j] = (floatx4){0.f, 0.f, 0.f, 0.f};

    bf16x8 aF[8], bL[4], bH[4];

// Half-iteration: compute tile in `buf`; stage both B halves (obuf,tB) at
// p0, A(buf,tA) at p3. One barrier per phase END.
#define HALF(buf, obuf, tB, tA, SB, SA, LASTVM) do {                          \
        /* p0 */                                                              \
        LDA8(buf, 0); LDB4(bL, buf, 0);                                       \
        if (SB) { STAGE_B(obuf, tB, 0); STAGE_B(obuf, tB, 1); }               \
        LGKM0(); MFMA_Q(0, 0, bL); BAR();                                     \
        /* p1 */                                                              \
        LDB4(bH, buf, 2);                                                     \
        LGKM0(); MFMA_Q(0, 2, bH); BAR();                                     \
        /* p2 */                                                              \
        LDA8(buf, 4);                                                         \
        LGKM0(); MFMA_Q(4, 2, bH); BAR();                                     \
        /* p3 */                                                              \
        if (SA) STAGE_A(buf, tA);                                             \
        MFMA_Q(4, 0, bL);                                                     \
        if (SA) { VMCNT4(); } else { LASTVM; }                                \
        BAR();                                                                \
    } while (0)

    // ---- prologue: tile0 (A+B) -> buf0, tile1 A -> buf1; A(1,1) stays in flight
    STAGE_A(0, 0);
    STAGE_B(0, 0, 0); STAGE_B(0, 0, 1);
    STAGE_A(1, 1);
    VMCNT4();
    BAR();

    // K = 1024 -> 16 K-tiles -> 7 full double-iterations + peeled tail.
#pragma unroll 1
    for (int it = 0; it < 7; ++it) {
        const int T = it * 2;
        HALF(0, 1, T + 1, T + 2, true, true, (void)0);
        HALF(1, 0, T + 2, T + 3, true, true, (void)0);
    }
    // tail: tile14 stages B(1,15) then fully drains; tile15 stages nothing.
    HALF(0, 1, 15, 0, true, false, VMCNT0());
    HALF(1, 0, 0, 0, false, false, (void)0);

    // ---- epilogue: dist = x2[row] + c2[col] - 2*xc
    // C/D layout: col = lane&15, row = quad*4 + reg. Plain stores (L2 merges;
    // round-0 WRITE_SIZE was exactly the 262 MB ideal; NT regressed).
    float c2v[4];
#pragma unroll
    for (int nf = 0; nf < 4; ++nf) c2v[nf] = c2[blockCol + wn * 64 + nf * 16 + l16];

#pragma unroll
    for (int mf = 0; mf < 8; ++mf) {
        const int rowb = blockRow + wm * 128 + mf * 16 + quad * 4;
        float x2v[4];
#pragma unroll
        for (int r = 0; r < 4; ++r) x2v[r] = x2[rowb + r];
#pragma unroll
        for (int nf = 0; nf < 4; ++nf) {
            const int col = blockCol + wn * 64 + nf * 16 + l16;
            float* o = out + (size_t)rowb * N + col;
#pragma unroll
            for (int r = 0; r < 4; ++r)
                o[(size_t)r * N] = fmaf(-2.0f, acc[mf][nf][r], x2v[r] + c2v[nf]);
        }
    }

#undef HALF
#undef MFMA_Q
#undef VMCNT0
#undef VMCNT4
#undef LGKM0
#undef BAR
#undef LDB4
#undef LDA8
#undef RD_B
#undef RD_A
#undef STAGE_B
#undef STAGE_A
}

// -------- fallback (only if ws_size too small / shape mismatch)
__global__ __launch_bounds__(256) void dist_fallback(
    const float* __restrict__ A, const float* __restrict__ B,
    float* __restrict__ out, int M, int N, int K)
{
    __shared__ float sA[64][17];
    __shared__ float sB[64][17];
    const int tid = threadIdx.x;
    const int tx = tid & 15;
    const int ty = tid >> 4;
    const int rowBase = blockIdx.y * 64;
    const int colBase = blockIdx.x * 64;
    float acc[4][4] = {};
    for (int k0 = 0; k0 < K; k0 += 16) {
        __syncthreads();
        {
            const int r = tid >> 2, c = (tid & 3) * 4;
            float4 va = *(const float4*)(A + (size_t)(rowBase + r) * K + k0 + c);
            sA[r][c] = va.x; sA[r][c + 1] = va.y; sA[r][c + 2] = va.z; sA[r][c + 3] = va.w;
            float4 vb = *(const float4*)(B + (size_t)(colBase + r) * K + k0 + c);
            sB[r][c] = vb.x; sB[r][c + 1] = vb.y; sB[r][c + 2] = vb.z; sB[r][c + 3] = vb.w;
        }
        __syncthreads();
#pragma unroll
        for (int kk = 0; kk < 16; kk++) {
            float ra[4], rb[4];
#pragma unroll
            for (int i = 0; i < 4; i++) ra[i] = sA[ty * 4 + i][kk];
#pragma unroll
            for (int j = 0; j < 4; j++) rb[j] = sB[tx * 4 + j][kk];
#pragma unroll
            for (int i = 0; i < 4; i++)
#pragma unroll
                for (int j = 0; j < 4; j++) {
                    float d = ra[i] - rb[j];
                    acc[i][j] = fmaf(d, d, acc[i][j]);
                }
        }
    }
#pragma unroll
    for (int i = 0; i < 4; i++)
#pragma unroll
        for (int j = 0; j < 4; j++)
            out[(size_t)(rowBase + ty * 4 + i) * N + (colBase + tx * 4 + j)] = acc[i][j];
}

extern "C" void kernel_launch(void* const* d_in, const int* in_sizes, int n_in,
                              void* d_out, int out_size, void* d_ws, size_t ws_size,
                              hipStream_t stream) {
    const float* feat = (const float*)d_in[0];
    const float* cent = (const float*)d_in[1];
    float* out = (float*)d_out;

    const int D = 1024;
    const int M = in_sizes[0] / D;   // 16384
    const int N = in_sizes[1] / D;   // 4096

    const size_t offA  = 0;
    const size_t offB  = offA + (size_t)M * D * sizeof(unsigned short);
    const size_t offX2 = offB + (size_t)N * D * sizeof(unsigned short);
    const size_t offC2 = offX2 + (size_t)M * sizeof(float);
    const size_t need  = offC2 + (size_t)N * sizeof(float);

    // fast path needs M%8192==0 (row-slab mapping: gy/8 multiple of 4),
    // N%256==0, D==1024 (hardcoded K), and the bf16 workspace.
    if (ws_size >= need && (M % 8192) == 0 && (N % 256) == 0) {
        unsigned short* Ab = (unsigned short*)((char*)d_ws + offA);
        unsigned short* Bb = (unsigned short*)((char*)d_ws + offB);
        float* x2 = (float*)((char*)d_ws + offX2);
        float* c2 = (float*)((char*)d_ws + offC2);

        cast_norm2<<<(M + N) / 4, 256, 0, stream>>>(feat, cent, Ab, Bb, x2, c2, M);
        dist_gemm<<<dim3(N / 256, M / 256), 512, 0, stream>>>(Ab, Bb, x2, c2, out, M, N);
    } else {
        dist_fallback<<<dim3(N / 64, M / 64), 256, 0, stream>>>(feat, cent, out, M, N, D);
    }
}